// Round 4
// baseline (150.903 us; speedup 1.0000x reference)
//
#include <hip/hip_runtime.h>
#include <hip/hip_bf16.h>

// Node_GAT N=16, M=1024, D=64, H=4.
// R8 = R7 (passing, 149.8us) + two changes:
//  (1) proj merged: grid (256,4) — one block stages x once, preloads A-frags to regs,
//      loops mat=K,Q,V (was 3 separate blocks re-staging x; 3072 -> 1024 blocks).
//  (2) attn: s_setprio(1) around S-MFMA and PV-MFMA clusters (T5; wave role diversity),
//      lac split into 2 accumulators (halve serial fp-add chain).
// attn structure unchanged from R7: wave-local P (S^T = mfma(Q,K)), exp2 in-reg,
// cvt_pk+permlane32_swap -> PV A-frags, 128 i-rows/block, double-buffered Q/V LDS,
// 1 barrier/j-tile, K pre-scaled by log2e, XCD-bijective block swizzle.

#define NB 16
#define MM 1024
#define DD 64
#define HH 4
#define NEG 0.2f
#define AST 72   // LDS row stride (shorts): 16B-aligned rows
#define DST 264  // dec LDS stride (256-wide rows)
#define LOG2E 1.44269504088896f

typedef __attribute__((ext_vector_type(8))) short bf16x8;
typedef __attribute__((ext_vector_type(8))) _Float16 f16x8;
typedef __attribute__((ext_vector_type(16))) float f32x16;
typedef __attribute__((ext_vector_type(4))) unsigned int uint4v;
typedef __attribute__((ext_vector_type(2))) unsigned int uint2v;

__device__ inline unsigned short f2bf(float f) {
  unsigned int u = __builtin_bit_cast(unsigned int, f);
  unsigned int r = (u + 0x7FFFu + ((u >> 16) & 1u)) >> 16;
  return (unsigned short)r;
}
__device__ inline unsigned short f2h(float f) {
  _Float16 h = (_Float16)f;
  return __builtin_bit_cast(unsigned short, h);
}
__device__ inline unsigned int pk_bf16(float lo, float hi) {
  unsigned int r;
  asm("v_cvt_pk_bf16_f32 %0, %1, %2" : "=v"(r) : "v"(lo), "v"(hi));
  return r;
}
// swap32(a,b): a' = {hf0: own.a, hf1: partner.b}; b' = {hf0: partner.a, hf1: own.b}
__device__ inline void swap32(unsigned int& a, unsigned int& b) {
  uint2v r = __builtin_amdgcn_permlane32_swap(a, b, false, false);
  a = r.x;
  b = r.y;
}

// ---------------- Kernel 0: weight prep -> f16 ----------------
__global__ __launch_bounds__(256) void prep_kernel(
    const float* __restrict__ Wk, const float* __restrict__ Wq,
    const float* __restrict__ Wv, const float* __restrict__ Wdec,
    unsigned short* __restrict__ Wf) {
  const int idx = (blockIdx.x * 256 + threadIdx.x) * 4;
  const int seg = idx >> 14, local = idx & 16383;
  const float* src = seg == 0 ? Wk : seg == 1 ? Wq : seg == 2 ? Wv : Wdec;
  float4 v = *(const float4*)&src[local];
  unsigned short p[4] = {f2h(v.x), f2h(v.y), f2h(v.z), f2h(v.w)};
  *(uint2*)&Wf[idx] = *(uint2*)p;
}

// ---------------- Kernel 1: projections (merged K,Q,V), f16 32x32x16 ----------------
// grid (256, 4): 64 m-rows x head. Stage x once, A-frags in regs, loop mat=0..2.
// K (scaled by log2e), Q -> f16 (n,h,m,e); V -> bf16 Vt (n,h,e,m).
__global__ __launch_bounds__(256) void proj_kernel(
    const float* __restrict__ x, const unsigned short* __restrict__ Wf,
    const float* __restrict__ bk, const float* __restrict__ bq, const float* __restrict__ bv,
    unsigned short* __restrict__ Kf, unsigned short* __restrict__ Qf,
    unsigned short* __restrict__ Vtg) {
  __shared__ unsigned short xs[64 * AST];
  __shared__ unsigned short ob[64 * AST];
  const int t = threadIdx.x;
  const int r0 = blockIdx.x * 64;
  const int h = blockIdx.y;
  const int n = r0 >> 10, ml = r0 & 1023;

#pragma unroll
  for (int rep = 0; rep < 2; ++rep) {
    int idx = rep * 256 + t, row = idx >> 3, c8 = (idx & 7) * 8;
    float4 a = *(const float4*)&x[(size_t)(r0 + row) * DD + c8];
    float4 b = *(const float4*)&x[(size_t)(r0 + row) * DD + c8 + 4];
    unsigned short p[8] = {f2h(a.x), f2h(a.y), f2h(a.z), f2h(a.w),
                           f2h(b.x), f2h(b.y), f2h(b.z), f2h(b.w)};
    *(uint4*)&xs[row * AST + c8] = *(uint4*)p;
  }
  __syncthreads();

  const int w = t >> 6, lane = t & 63, m31 = lane & 31, hf = lane >> 5;
  const int mi = w >> 1, ne = w & 1;
  const int ecol = h * 64 + ne * 32 + m31;

  // preload A-frags once; reused for all 3 mats
  f16x8 xa[4];
#pragma unroll
  for (int ks = 0; ks < 4; ++ks)
    xa[ks] = *(f16x8*)&xs[(mi * 32 + m31) * AST + ks * 16 + hf * 8];

#pragma unroll
  for (int mat = 0; mat < 3; ++mat) {
    const float* bias = mat == 0 ? bk : (mat == 1 ? bq : bv);
    const float bb = bias[ecol];

    f32x16 C;
#pragma unroll
    for (int r = 0; r < 16; ++r) C[r] = 0.f;
#pragma unroll
    for (int ks = 0; ks < 4; ++ks) {
      f16x8 wb = *(const f16x8*)&Wf[(size_t)mat * 16384 + (size_t)ecol * DD + ks * 16 + hf * 8];
      C = __builtin_amdgcn_mfma_f32_32x32x16_f16(xa[ks], wb, C, 0, 0, 0);
    }

    if (mat < 2) {
      const float ksc = (mat == 0) ? LOG2E : 1.0f;  // fold exp's log2e into K
#pragma unroll
      for (int r = 0; r < 16; ++r) {
        int rr = (r & 3) + 8 * (r >> 2) + 4 * hf;
        ob[(mi * 32 + rr) * AST + ne * 32 + m31] = f2h((C[r] + bb) * ksc);
      }
    } else {
#pragma unroll
      for (int r = 0; r < 16; ++r) {
        int rr = (r & 3) + 8 * (r >> 2) + 4 * hf;
        ob[(ne * 32 + m31) * AST + mi * 32 + rr] = f2bf(C[r] + bb);
      }
    }
    __syncthreads();

    if (mat < 2) {
      unsigned short* dst = mat == 0 ? Kf : Qf;
      const size_t obase = (((size_t)n * HH + h) * MM + ml) * DD;
#pragma unroll
      for (int rep = 0; rep < 2; ++rep) {
        int idx = rep * 256 + t, row = idx >> 3, c8 = (idx & 7) * 8;
        *(uint4*)&dst[obase + (size_t)row * DD + c8] = *(uint4*)&ob[row * AST + c8];
      }
    } else {
      const size_t obase = (((size_t)n * HH + h) * DD) * MM + ml;
#pragma unroll
      for (int rep = 0; rep < 2; ++rep) {
        int idx = rep * 256 + t, row = idx >> 3, c8 = (idx & 7) * 8;
        *(uint4*)&Vtg[obase + (size_t)row * MM + c8] = *(uint4*)&ob[row * AST + c8];
      }
    }
    __syncthreads();  // ob reuse guard before next mat
  }
}

// ---------------- Kernel 2: flash attention, wave-local P ----------------
// grid (8, H, N), 256 thr = 4 waves. Block: 128 i x 1024 j; wave w owns i-strip w*32..+32.
// Per j-tile (64 j): S^T = mfma(Q_j, K_i) -> lane (m31,hf) holds P[i=m31][j=crow(r,hf)];
// exp2 in-reg; cvt_pk+permlane32_swap -> PV A-frags; PV vs V^T (LDS). 1 barrier/tile.
__global__ __launch_bounds__(256, 2) void attn_kernel(
    const unsigned short* __restrict__ Kf, const unsigned short* __restrict__ Qf,
    const unsigned short* __restrict__ Vtg, const float* __restrict__ x,
    unsigned short* __restrict__ DX) {
  __shared__ __align__(16) unsigned short sm[4 * 64 * AST];  // qh[2] | vt[2]; epilogue reuses
  __shared__ float ls[128];                                  // per-row softmax denom

  const int t = threadIdx.x;
  const int w = t >> 6, lane = t & 63;
  const int m31 = lane & 31, hf = lane >> 5;

  // XCD-bijective swizzle: xcd = slot&7 gets 8 whole (n,h) groups.
  const int slot = blockIdx.x + 8 * (blockIdx.y + HH * (int)blockIdx.z);  // 0..511
  const int xcd = slot & 7, within = slot >> 3;
  const int grp = xcd * 8 + (within >> 3);  // 0..63 = n*4+h
  const int ib = within & 7;
  const int n = grp >> 2, h = grp & 3;
  const int i0 = ib * 128;

  const size_t base = (((size_t)n * HH + h) * MM) * DD;
  const size_t baseT = (((size_t)n * HH + h) * DD) * MM;
  const unsigned short* Qp = Qf + base;
  const unsigned short* Vp = Vtg + baseT;

  // K fragments: B-operand cols i = i0 + w*32 + m31 (log2e pre-folded in proj)
  f16x8 kfrag[4];
#pragma unroll
  for (int ks = 0; ks < 4; ++ks)
    kfrag[ks] = *(const f16x8*)&Kf[base + (size_t)(i0 + w * 32 + m31) * DD + ks * 16 + hf * 8];

  const int r0 = t >> 3, c8 = (t & 7) * 8;

  // prologue: stage tile 0 into buffer 0
  {
    uint4 qa = *(const uint4*)&Qp[(size_t)r0 * DD + c8];
    uint4 qb2 = *(const uint4*)&Qp[(size_t)(r0 + 32) * DD + c8];
    uint4 va = *(const uint4*)&Vp[(size_t)r0 * MM + c8];
    uint4 vb2 = *(const uint4*)&Vp[(size_t)(r0 + 32) * MM + c8];
    *(uint4*)&sm[r0 * AST + c8] = qa;
    *(uint4*)&sm[(r0 + 32) * AST + c8] = qb2;
    unsigned short* vb0 = sm + 2 * 64 * AST;
    *(uint4*)&vb0[r0 * AST + c8] = va;
    *(uint4*)&vb0[(r0 + 32) * AST + c8] = vb2;
  }
  __syncthreads();

  f32x16 agg0, agg1;
#pragma unroll
  for (int r = 0; r < 16; ++r) { agg0[r] = 0.f; agg1[r] = 0.f; }
  float lacA = 0.f, lacB = 0.f;

  uint4 qrA, qrB, vrA, vrB;

#pragma unroll 2
  for (int jt = 0; jt < 16; ++jt) {
    unsigned short* qb = sm + (jt & 1) * (64 * AST);
    unsigned short* vb = sm + (2 + (jt & 1)) * (64 * AST);

    // prefetch next tile into regs (consumed by ds_write after compute)
    if (jt < 15) {
      const int j0n = (jt + 1) * 64;
      qrA = *(const uint4*)&Qp[(size_t)(j0n + r0) * DD + c8];
      qrB = *(const uint4*)&Qp[(size_t)(j0n + r0 + 32) * DD + c8];
      vrA = *(const uint4*)&Vp[(size_t)r0 * MM + j0n + c8];
      vrB = *(const uint4*)&Vp[(size_t)(r0 + 32) * MM + j0n + c8];
    }

    // S^T tiles: D[j][i] = mfma(A=Q rows j, B=K cols i). Lane (m31,hf) reg r:
    // j_loc = (r&3)+8*(r>>2)+4*hf, i = m31. Then P=exp2(leaky) in-reg; pack A-frags.
    bf16x8 pa[4];
#pragma unroll
    for (int tile = 0; tile < 2; ++tile) {
      f32x16 C;
#pragma unroll
      for (int r = 0; r < 16; ++r) C[r] = 0.f;
      __builtin_amdgcn_s_setprio(1);
#pragma unroll
      for (int ks = 0; ks < 4; ++ks) {
        f16x8 qa = *(f16x8*)&qb[(tile * 32 + m31) * AST + ks * 16 + hf * 8];
        C = __builtin_amdgcn_mfma_f32_32x32x16_f16(qa, kfrag[ks], C, 0, 0, 0);
      }
      __builtin_amdgcn_s_setprio(0);
#pragma unroll
      for (int r = 0; r < 16; ++r) {
        float s = C[r];
        s = fmaxf(s, NEG * s);  // leaky (log2e scale commutes with max)
        s = __builtin_amdgcn_exp2f(s);
        if (r & 1) lacB += s; else lacA += s;
        C[r] = s;
      }
      // PV A-frag (k-slice j_loc 0..15 of this S-tile): elements jj -> j_loc = hf*8+jj.
      // swap32(pk01, pk45) -> (w0, w2); swap32(pk23, pk67) -> (w1, w3).
      {
        unsigned int p01 = pk_bf16(C[0], C[1]), p23 = pk_bf16(C[2], C[3]);
        unsigned int p45 = pk_bf16(C[4], C[5]), p67 = pk_bf16(C[6], C[7]);
        swap32(p01, p45);
        swap32(p23, p67);
        uint4v wlo = {p01, p23, p45, p67};
        pa[2 * tile] = __builtin_bit_cast(bf16x8, wlo);
      }
      // k-slice j_loc 16..31: same with C8..C15
      {
        unsigned int p89 = pk_bf16(C[8], C[9]), pAB = pk_bf16(C[10], C[11]);
        unsigned int pCD = pk_bf16(C[12], C[13]), pEF = pk_bf16(C[14], C[15]);
        swap32(p89, pCD);
        swap32(pAB, pEF);
        uint4v whi = {p89, pAB, pCD, pEF};
        pa[2 * tile + 1] = __builtin_bit_cast(bf16x8, whi);
      }
    }

    // PV: agg[i][e] += P[i][j] * V[j][e] (B from V^T rows e in LDS)
    __builtin_amdgcn_s_setprio(1);
#pragma unroll
    for (int ks = 0; ks < 4; ++ks) {
      bf16x8 bv0 = *(bf16x8*)&vb[m31 * AST + ks * 16 + hf * 8];
      bf16x8 bv1 = *(bf16x8*)&vb[(32 + m31) * AST + ks * 16 + hf * 8];
      agg0 = __builtin_amdgcn_mfma_f32_32x32x16_bf16(pa[ks], bv0, agg0, 0, 0, 0);
      agg1 = __builtin_amdgcn_mfma_f32_32x32x16_bf16(pa[ks], bv1, agg1, 0, 0, 0);
    }
    __builtin_amdgcn_s_setprio(0);

    // write next tile into the other buffer (no reader this iteration)
    if (jt < 15) {
      unsigned short* qn = sm + ((jt & 1) ^ 1) * (64 * AST);
      unsigned short* vn = sm + (2 + ((jt & 1) ^ 1)) * (64 * AST);
      *(uint4*)&qn[r0 * AST + c8] = qrA;
      *(uint4*)&qn[(r0 + 32) * AST + c8] = qrB;
      *(uint4*)&vn[r0 * AST + c8] = vrA;
      *(uint4*)&vn[(r0 + 32) * AST + c8] = vrB;
    }
    __syncthreads();
  }

  // denom: lane's lac covers its crow-set for column i=m31; pair-sum gives full l[i=m31].
  // Broadcast via LDS since agg rows are crow(r,hf), not m31.
  const float lac = lacA + lacB;
  const float lsum = lac + __shfl_xor(lac, 32);
  if (hf == 0) ls[w * 32 + m31] = lsum;
  __syncthreads();

  // epilogue: dx = leaky(agg/l) - x -> f16 stage in sm -> coalesced store (concat layout)
#pragma unroll
  for (int r = 0; r < 16; ++r) {
    const int rr = (r & 3) + 8 * (r >> 2) + 4 * hf;
    const float rl = 1.0f / ls[w * 32 + rr];
    const size_t xrow = ((size_t)n * MM + i0 + w * 32 + rr) * DD;
    float v0 = agg0[r] * rl;
    v0 = fmaxf(v0, NEG * v0);
    v0 -= x[xrow + m31];
    sm[(w * 32 + rr) * AST + m31] = f2h(v0);
    float v1 = agg1[r] * rl;
    v1 = fmaxf(v1, NEG * v1);
    v1 -= x[xrow + 32 + m31];
    sm[(w * 32 + rr) * AST + 32 + m31] = f2h(v1);
  }
  __syncthreads();
#pragma unroll
  for (int rep = 0; rep < 4; ++rep) {
    const int idx = rep * 256 + t, row = idx >> 3, cc = (idx & 7) * 8;
    *(uint4*)&DX[((size_t)n * MM + i0 + row) * (HH * DD) + h * DD + cc] =
        *(uint4*)&sm[row * AST + cc];
  }
}

// ---------------- Kernel 3: decoder, f16 32x32x16 MFMA ----------------
__global__ __launch_bounds__(256) void dec_kernel(
    const unsigned short* __restrict__ DX, const unsigned short* __restrict__ Wdf,
    const float* __restrict__ bdec, float* __restrict__ out) {
  __shared__ unsigned short dxs[64 * DST];
  const int t = threadIdx.x;
  const int w = t >> 6, lane = t & 63, m31 = lane & 31, hf = lane >> 5;
  const int mi = w >> 1, nd = w & 1;
  const int r0 = blockIdx.x * 64;
#pragma unroll
  for (int rep = 0; rep < 8; ++rep) {
    int idx = rep * 256 + t, row = idx >> 5, c8 = (idx & 31) * 8;
    *(uint4*)&dxs[row * DST + c8] = *(const uint4*)&DX[(size_t)(r0 + row) * 256 + c8];
  }
  __syncthreads();
  const float bb = bdec[nd * 32 + m31];
  f32x16 C;
#pragma unroll
  for (int r = 0; r < 16; ++r) C[r] = 0.f;
#pragma unroll
  for (int ks = 0; ks < 16; ++ks) {
    f16x8 aD = *(f16x8*)&dxs[(mi * 32 + m31) * DST + ks * 16 + hf * 8];
    f16x8 bW = *(const f16x8*)&Wdf[(size_t)(nd * 32 + m31) * 256 + ks * 16 + hf * 8];
    C = __builtin_amdgcn_mfma_f32_32x32x16_f16(aD, bW, C, 0, 0, 0);
  }
#pragma unroll
  for (int r = 0; r < 16; ++r) {
    int rr = (r & 3) + 8 * (r >> 2) + 4 * hf;
    out[(size_t)(r0 + mi * 32 + rr) * DD + nd * 32 + m31] = C[r] + bb;
  }
}

extern "C" void kernel_launch(void* const* d_in, const int* in_sizes, int n_in,
                              void* d_out, int out_size, void* d_ws, size_t ws_size,
                              hipStream_t stream) {
  const float* x    = (const float*)d_in[0];
  const float* Wk   = (const float*)d_in[2];
  const float* bk   = (const float*)d_in[3];
  const float* Wq   = (const float*)d_in[4];
  const float* bq   = (const float*)d_in[5];
  const float* Wv   = (const float*)d_in[6];
  const float* bv   = (const float*)d_in[7];
  const float* Wdec = (const float*)d_in[8];
  const float* bdec = (const float*)d_in[9];
  float* out = (float*)d_out;

  const size_t seg = (size_t)NB * HH * MM * DD;
  unsigned short* Kf  = (unsigned short*)d_ws;
  unsigned short* Qf  = Kf + seg;
  unsigned short* Vt  = Qf + seg;
  unsigned short* DXp = Vt + seg;
  unsigned short* Wf  = DXp + seg;
  unsigned short* Wdf = Wf + 3 * 16384;

  prep_kernel<<<64, 256, 0, stream>>>(Wk, Wq, Wv, Wdec, Wf);
  proj_kernel<<<dim3(256, 4), 256, 0, stream>>>(x, Wf, bk, bq, bv, Kf, Qf, Vt);
  attn_kernel<<<dim3(8, HH, NB), 256, 0, stream>>>(Kf, Qf, Vt, x, DXp);
  dec_kernel<<<NB * MM / 64, 256, 0, stream>>>(DXp, Wdf, bdec, out);
}

// Round 6
// 149.476 us; speedup vs baseline: 1.0096x; 1.0096x over previous
//
#include <hip/hip_runtime.h>
#include <hip/hip_bf16.h>

// Node_GAT N=16, M=1024, D=64, H=4.
// R10 = R9 resubmitted byte-identical (R9's bench was an infra failure: container
// died twice, no signal). Deferred-PV software pipeline in attn (T15 analog):
//   PV(jt-1) executes between softmax(t0) and S(t1) of iter jt -> its 8 MFMAs are
//   independent of iter jt's S/softmax chain, so the scheduler can fill the MFMA pipe
//   during softmax VALU and vice versa. pa held in regs one iter (pa[2][4], literal
//   indices via g*4+k nest); V rotated through 4 LDS slots (read jt-1, write jt+1).
// attn core unchanged otherwise: wave-local P (S^T = mfma(Q,K)), exp2 in-reg,
// cvt_pk+permlane32_swap -> PV A-frags, 128 i-rows/block, 1 barrier/j-tile,
// K pre-scaled by log2e, XCD-bijective block swizzle.

#define NB 16
#define MM 1024
#define DD 64
#define HH 4
#define NEG 0.2f
#define AST 72   // LDS row stride (shorts): 16B-aligned rows
#define SLOT (64 * AST)
#define DST 264  // dec LDS stride (256-wide rows)
#define LOG2E 1.44269504088896f

typedef __attribute__((ext_vector_type(8))) short bf16x8;
typedef __attribute__((ext_vector_type(8))) _Float16 f16x8;
typedef __attribute__((ext_vector_type(16))) float f32x16;
typedef __attribute__((ext_vector_type(4))) unsigned int uint4v;
typedef __attribute__((ext_vector_type(2))) unsigned int uint2v;

__device__ inline unsigned short f2bf(float f) {
  unsigned int u = __builtin_bit_cast(unsigned int, f);
  unsigned int r = (u + 0x7FFFu + ((u >> 16) & 1u)) >> 16;
  return (unsigned short)r;
}
__device__ inline unsigned short f2h(float f) {
  _Float16 h = (_Float16)f;
  return __builtin_bit_cast(unsigned short, h);
}
__device__ inline unsigned int pk_bf16(float lo, float hi) {
  unsigned int r;
  asm("v_cvt_pk_bf16_f32 %0, %1, %2" : "=v"(r) : "v"(lo), "v"(hi));
  return r;
}
// swap32(a,b): a' = {hf0: own.a, hf1: partner.b}; b' = {hf0: partner.a, hf1: own.b}
__device__ inline void swap32(unsigned int& a, unsigned int& b) {
  uint2v r = __builtin_amdgcn_permlane32_swap(a, b, false, false);
  a = r.x;
  b = r.y;
}

// ---------------- Kernel 0: weight prep -> f16 ----------------
__global__ __launch_bounds__(256) void prep_kernel(
    const float* __restrict__ Wk, const float* __restrict__ Wq,
    const float* __restrict__ Wv, const float* __restrict__ Wdec,
    unsigned short* __restrict__ Wf) {
  const int idx = (blockIdx.x * 256 + threadIdx.x) * 4;
  const int seg = idx >> 14, local = idx & 16383;
  const float* src = seg == 0 ? Wk : seg == 1 ? Wq : seg == 2 ? Wv : Wdec;
  float4 v = *(const float4*)&src[local];
  unsigned short p[4] = {f2h(v.x), f2h(v.y), f2h(v.z), f2h(v.w)};
  *(uint2*)&Wf[idx] = *(uint2*)p;
}

// ---------------- Kernel 1: projections, f16 32x32x16 MFMA ----------------
// grid (256, 12): 64 m-rows x combo(mat*4+h). K (scaled by log2e), Q -> f16 (n,h,m,e);
// V -> bf16 Vt (n,h,e,m).
__global__ __launch_bounds__(256) void proj_kernel(
    const float* __restrict__ x, const unsigned short* __restrict__ Wf,
    const float* __restrict__ bk, const float* __restrict__ bq, const float* __restrict__ bv,
    unsigned short* __restrict__ Kf, unsigned short* __restrict__ Qf,
    unsigned short* __restrict__ Vtg) {
  __shared__ unsigned short xs[64 * AST];
  __shared__ unsigned short ob[64 * AST];
  const int t = threadIdx.x;
  const int r0 = blockIdx.x * 64;
  const int combo = blockIdx.y, mat = combo >> 2, h = combo & 3;
  const int n = r0 >> 10, ml = r0 & 1023;
  const float* bias = mat == 0 ? bk : (mat == 1 ? bq : bv);

#pragma unroll
  for (int rep = 0; rep < 2; ++rep) {
    int idx = rep * 256 + t, row = idx >> 3, c8 = (idx & 7) * 8;
    float4 a = *(const float4*)&x[(size_t)(r0 + row) * DD + c8];
    float4 b = *(const float4*)&x[(size_t)(r0 + row) * DD + c8 + 4];
    unsigned short p[8] = {f2h(a.x), f2h(a.y), f2h(a.z), f2h(a.w),
                           f2h(b.x), f2h(b.y), f2h(b.z), f2h(b.w)};
    *(uint4*)&xs[row * AST + c8] = *(uint4*)p;
  }
  __syncthreads();

  const int w = t >> 6, lane = t & 63, m31 = lane & 31, hf = lane >> 5;
  const int mi = w >> 1, ne = w & 1;
  const int ecol = h * 64 + ne * 32 + m31;
  const float bb = bias[ecol];

  f32x16 C;
#pragma unroll
  for (int r = 0; r < 16; ++r) C[r] = 0.f;
#pragma unroll
  for (int ks = 0; ks < 4; ++ks) {
    f16x8 xa = *(f16x8*)&xs[(mi * 32 + m31) * AST + ks * 16 + hf * 8];
    f16x8 wb = *(const f16x8*)&Wf[(size_t)mat * 16384 + (size_t)ecol * DD + ks * 16 + hf * 8];
    C = __builtin_amdgcn_mfma_f32_32x32x16_f16(xa, wb, C, 0, 0, 0);
  }

  if (mat < 2) {
    const float ksc = (mat == 0) ? LOG2E : 1.0f;  // fold exp's log2e into K
#pragma unroll
    for (int r = 0; r < 16; ++r) {
      int rr = (r & 3) + 8 * (r >> 2) + 4 * hf;
      ob[(mi * 32 + rr) * AST + ne * 32 + m31] = f2h((C[r] + bb) * ksc);
    }
  } else {
#pragma unroll
    for (int r = 0; r < 16; ++r) {
      int rr = (r & 3) + 8 * (r >> 2) + 4 * hf;
      ob[(ne * 32 + m31) * AST + mi * 32 + rr] = f2bf(C[r] + bb);
    }
  }
  __syncthreads();

  if (mat < 2) {
    unsigned short* dst = mat == 0 ? Kf : Qf;
    const size_t obase = (((size_t)n * HH + h) * MM + ml) * DD;
#pragma unroll
    for (int rep = 0; rep < 2; ++rep) {
      int idx = rep * 256 + t, row = idx >> 3, c8 = (idx & 7) * 8;
      *(uint4*)&dst[obase + (size_t)row * DD + c8] = *(uint4*)&ob[row * AST + c8];
    }
  } else {
    const size_t obase = (((size_t)n * HH + h) * DD) * MM + ml;
#pragma unroll
    for (int rep = 0; rep < 2; ++rep) {
      int idx = rep * 256 + t, row = idx >> 3, c8 = (idx & 7) * 8;
      *(uint4*)&Vtg[obase + (size_t)row * MM + c8] = *(uint4*)&ob[row * AST + c8];
    }
  }
}

// ---------------- Kernel 2: flash attention, wave-local P + deferred PV ----------------
// grid (8, H, N), 256 thr = 4 waves. Block: 128 i x 1024 j; wave w owns i-strip w*32..+32.
// Iter jt: S^T(jt) tile0 -> softmax(t0) -> PV(jt-1) [independent: overlaps softmax] ->
// S^T(jt) tile1 -> softmax(t1) -> stage jt+1 -> barrier. Final PV after loop.
// Q: 2 LDS slots; V: 4 LDS slots (PV reads slot jt-1 while slot jt+1 is written).
__global__ __launch_bounds__(256, 2) void attn_kernel(
    const unsigned short* __restrict__ Kf, const unsigned short* __restrict__ Qf,
    const unsigned short* __restrict__ Vtg, const float* __restrict__ x,
    unsigned short* __restrict__ DX) {
  __shared__ __align__(16) unsigned short sm[6 * SLOT];  // q[2] | v[4]; epilogue reuses
  __shared__ float ls[128];                              // per-row softmax denom

  const int t = threadIdx.x;
  const int w = t >> 6, lane = t & 63;
  const int m31 = lane & 31, hf = lane >> 5;

  // XCD-bijective swizzle: xcd = slot&7 gets 8 whole (n,h) groups.
  const int slot = blockIdx.x + 8 * (blockIdx.y + HH * (int)blockIdx.z);  // 0..511
  const int xcd = slot & 7, within = slot >> 3;
  const int grp = xcd * 8 + (within >> 3);  // 0..63 = n*4+h
  const int ib = within & 7;
  const int n = grp >> 2, h = grp & 3;
  const int i0 = ib * 128;

  const size_t base = (((size_t)n * HH + h) * MM) * DD;
  const size_t baseT = (((size_t)n * HH + h) * DD) * MM;
  const unsigned short* Qp = Qf + base;
  const unsigned short* Vp = Vtg + baseT;

  unsigned short* qs = sm;             // 2 slots
  unsigned short* vs = sm + 2 * SLOT;  // 4 slots

  // K fragments: B-operand cols i = i0 + w*32 + m31 (log2e pre-folded in proj)
  f16x8 kfrag[4];
#pragma unroll
  for (int ks = 0; ks < 4; ++ks)
    kfrag[ks] = *(const f16x8*)&Kf[base + (size_t)(i0 + w * 32 + m31) * DD + ks * 16 + hf * 8];

  const int r0 = t >> 3, c8 = (t & 7) * 8;

  // prologue: stage tile 0 into q slot 0 / v slot 0
  {
    uint4 qa = *(const uint4*)&Qp[(size_t)r0 * DD + c8];
    uint4 qb2 = *(const uint4*)&Qp[(size_t)(r0 + 32) * DD + c8];
    uint4 va = *(const uint4*)&Vp[(size_t)r0 * MM + c8];
    uint4 vb2 = *(const uint4*)&Vp[(size_t)(r0 + 32) * MM + c8];
    *(uint4*)&qs[r0 * AST + c8] = qa;
    *(uint4*)&qs[(r0 + 32) * AST + c8] = qb2;
    *(uint4*)&vs[r0 * AST + c8] = va;
    *(uint4*)&vs[(r0 + 32) * AST + c8] = vb2;
  }
  __syncthreads();

  f32x16 agg0, agg1;
#pragma unroll
  for (int r = 0; r < 16; ++r) { agg0[r] = 0.f; agg1[r] = 0.f; }
  float lac = 0.f;

  uint4 qrA, qrB, vrA, vrB;
  bf16x8 pa[2][4];  // [jt&1][ks] — all indices compile-time via g*4+k nest

  for (int g = 0; g < 4; ++g) {
#pragma unroll
    for (int k = 0; k < 4; ++k) {
      const int jt = g * 4 + k;
      unsigned short* qb = qs + (k & 1) * SLOT;
      const bool haveNext = (k < 3) || (g < 3);

      // issue global prefetch for tile jt+1 (lands during compute; written at tail)
      if (haveNext) {
        const int j0n = (jt + 1) * 64;
        qrA = *(const uint4*)&Qp[(size_t)(j0n + r0) * DD + c8];
        qrB = *(const uint4*)&Qp[(size_t)(j0n + r0 + 32) * DD + c8];
        vrA = *(const uint4*)&Vp[(size_t)r0 * MM + j0n + c8];
        vrB = *(const uint4*)&Vp[(size_t)(r0 + 32) * MM + j0n + c8];
      }

      // ---- S tile0: D[j][i] = mfma(Q rows j, K cols i) ----
      f32x16 C;
#pragma unroll
      for (int r = 0; r < 16; ++r) C[r] = 0.f;
#pragma unroll
      for (int ks = 0; ks < 4; ++ks) {
        f16x8 qa = *(f16x8*)&qb[m31 * AST + ks * 16 + hf * 8];
        C = __builtin_amdgcn_mfma_f32_32x32x16_f16(qa, kfrag[ks], C, 0, 0, 0);
      }
      // softmax t0 -> pa[k&1][0..1]
#pragma unroll
      for (int r = 0; r < 16; ++r) {
        float s = C[r];
        s = fmaxf(s, NEG * s);
        s = __builtin_amdgcn_exp2f(s);
        lac += s;
        C[r] = s;
      }
      {
        unsigned int p01 = pk_bf16(C[0], C[1]), p23 = pk_bf16(C[2], C[3]);
        unsigned int p45 = pk_bf16(C[4], C[5]), p67 = pk_bf16(C[6], C[7]);
        swap32(p01, p45);
        swap32(p23, p67);
        uint4v wlo = {p01, p23, p45, p67};
        pa[k & 1][0] = __builtin_bit_cast(bf16x8, wlo);
        unsigned int p89 = pk_bf16(C[8], C[9]), pAB = pk_bf16(C[10], C[11]);
        unsigned int pCD = pk_bf16(C[12], C[13]), pEF = pk_bf16(C[14], C[15]);
        swap32(p89, pCD);
        swap32(pAB, pEF);
        uint4v whi = {p89, pAB, pCD, pEF};
        pa[k & 1][1] = __builtin_bit_cast(bf16x8, whi);
      }

      // ---- deferred PV(jt-1): independent of this iter's S/softmax ----
      if ((k > 0) || (g > 0)) {
        unsigned short* vbp = vs + ((k + 3) & 3) * SLOT;  // slot (jt-1)&3
#pragma unroll
        for (int ks = 0; ks < 4; ++ks) {
          bf16x8 bv0 = *(bf16x8*)&vbp[m31 * AST + ks * 16 + hf * 8];
          bf16x8 bv1 = *(bf16x8*)&vbp[(32 + m31) * AST + ks * 16 + hf * 8];
          agg0 = __builtin_amdgcn_mfma_f32_32x32x16_bf16(pa[(k + 1) & 1][ks], bv0, agg0, 0, 0, 0);
          agg1 = __builtin_amdgcn_mfma_f32_32x32x16_bf16(pa[(k + 1) & 1][ks], bv1, agg1, 0, 0, 0);
        }
      }

      // ---- S tile1 + softmax -> pa[k&1][2..3] ----
#pragma unroll
      for (int r = 0; r < 16; ++r) C[r] = 0.f;
#pragma unroll
      for (int ks = 0; ks < 4; ++ks) {
        f16x8 qa = *(f16x8*)&qb[(32 + m31) * AST + ks * 16 + hf * 8];
        C = __builtin_amdgcn_mfma_f32_32x32x16_f16(qa, kfrag[ks], C, 0, 0, 0);
      }
#pragma unroll
      for (int r = 0; r < 16; ++r) {
        float s = C[r];
        s = fmaxf(s, NEG * s);
        s = __builtin_amdgcn_exp2f(s);
        lac += s;
        C[r] = s;
      }
      {
        unsigned int p01 = pk_bf16(C[0], C[1]), p23 = pk_bf16(C[2], C[3]);
        unsigned int p45 = pk_bf16(C[4], C[5]), p67 = pk_bf16(C[6], C[7]);
        swap32(p01, p45);
        swap32(p23, p67);
        uint4v wlo = {p01, p23, p45, p67};
        pa[k & 1][2] = __builtin_bit_cast(bf16x8, wlo);
        unsigned int p89 = pk_bf16(C[8], C[9]), pAB = pk_bf16(C[10], C[11]);
        unsigned int pCD = pk_bf16(C[12], C[13]), pEF = pk_bf16(C[14], C[15]);
        swap32(p89, pCD);
        swap32(pAB, pEF);
        uint4v whi = {p89, pAB, pCD, pEF};
        pa[k & 1][3] = __builtin_bit_cast(bf16x8, whi);
      }

      // stage tile jt+1: q slot (jt+1)&1, v slot (jt+1)&3
      if (haveNext) {
        unsigned short* qn = qs + ((k + 1) & 1) * SLOT;
        unsigned short* vn = vs + ((k + 1) & 3) * SLOT;
        *(uint4*)&qn[r0 * AST + c8] = qrA;
        *(uint4*)&qn[(r0 + 32) * AST + c8] = qrB;
        *(uint4*)&vn[r0 * AST + c8] = vrA;
        *(uint4*)&vn[(r0 + 32) * AST + c8] = vrB;
      }
      __syncthreads();
    }
  }

  // final PV for jt=15: pa[1], v slot 3
  {
    unsigned short* vbp = vs + 3 * SLOT;
#pragma unroll
    for (int ks = 0; ks < 4; ++ks) {
      bf16x8 bv0 = *(bf16x8*)&vbp[m31 * AST + ks * 16 + hf * 8];
      bf16x8 bv1 = *(bf16x8*)&vbp[(32 + m31) * AST + ks * 16 + hf * 8];
      agg0 = __builtin_amdgcn_mfma_f32_32x32x16_bf16(pa[1][ks], bv0, agg0, 0, 0, 0);
      agg1 = __builtin_amdgcn_mfma_f32_32x32x16_bf16(pa[1][ks], bv1, agg1, 0, 0, 0);
    }
  }

  // denom: lane's lac covers its crow-set for column i=m31; pair-sum gives full l[i=m31].
  const float lsum = lac + __shfl_xor(lac, 32);
  if (hf == 0) ls[w * 32 + m31] = lsum;
  __syncthreads();

  // epilogue: dx = leaky(agg/l) - x -> f16 stage in sm -> coalesced store (concat layout)
#pragma unroll
  for (int r = 0; r < 16; ++r) {
    const int rr = (r & 3) + 8 * (r >> 2) + 4 * hf;
    const float rl = 1.0f / ls[w * 32 + rr];
    const size_t xrow = ((size_t)n * MM + i0 + w * 32 + rr) * DD;
    float v0 = agg0[r] * rl;
    v0 = fmaxf(v0, NEG * v0);
    v0 -= x[xrow + m31];
    sm[(w * 32 + rr) * AST + m31] = f2h(v0);
    float v1 = agg1[r] * rl;
    v1 = fmaxf(v1, NEG * v1);
    v1 -= x[xrow + 32 + m31];
    sm[(w * 32 + rr) * AST + 32 + m31] = f2h(v1);
  }
  __syncthreads();
#pragma unroll
  for (int rep = 0; rep < 4; ++rep) {
    const int idx = rep * 256 + t, row = idx >> 3, cc = (idx & 7) * 8;
    *(uint4*)&DX[((size_t)n * MM + i0 + row) * (HH * DD) + h * DD + cc] =
        *(uint4*)&sm[row * AST + cc];
  }
}

// ---------------- Kernel 3: decoder, f16 32x32x16 MFMA ----------------
__global__ __launch_bounds__(256) void dec_kernel(
    const unsigned short* __restrict__ DX, const unsigned short* __restrict__ Wdf,
    const float* __restrict__ bdec, float* __restrict__ out) {
  __shared__ unsigned short dxs[64 * DST];
  const int t = threadIdx.x;
  const int w = t >> 6, lane = t & 63, m31 = lane & 31, hf = lane >> 5;
  const int mi = w >> 1, nd = w & 1;
  const int r0 = blockIdx.x * 64;
#pragma unroll
  for (int rep = 0; rep < 8; ++rep) {
    int idx = rep * 256 + t, row = idx >> 5, c8 = (idx & 31) * 8;
    *(uint4*)&dxs[row * DST + c8] = *(const uint4*)&DX[(size_t)(r0 + row) * 256 + c8];
  }
  __syncthreads();
  const float bb = bdec[nd * 32 + m31];
  f32x16 C;
#pragma unroll
  for (int r = 0; r < 16; ++r) C[r] = 0.f;
#pragma unroll
  for (int ks = 0; ks < 16; ++ks) {
    f16x8 aD = *(f16x8*)&dxs[(mi * 32 + m31) * DST + ks * 16 + hf * 8];
    f16x8 bW = *(const f16x8*)&Wdf[(size_t)(nd * 32 + m31) * 256 + ks * 16 + hf * 8];
    C = __builtin_amdgcn_mfma_f32_32x32x16_f16(aD, bW, C, 0, 0, 0);
  }
#pragma unroll
  for (int r = 0; r < 16; ++r) {
    int rr = (r & 3) + 8 * (r >> 2) + 4 * hf;
    out[(size_t)(r0 + mi * 32 + rr) * DD + nd * 32 + m31] = C[r] + bb;
  }
}

extern "C" void kernel_launch(void* const* d_in, const int* in_sizes, int n_in,
                              void* d_out, int out_size, void* d_ws, size_t ws_size,
                              hipStream_t stream) {
  const float* x    = (const float*)d_in[0];
  const float* Wk   = (const float*)d_in[2];
  const float* bk   = (const float*)d_in[3];
  const float* Wq   = (const float*)d_in[4];
  const float* bq   = (const float*)d_in[5];
  const float* Wv   = (const float*)d_in[6];
  const float* bv   = (const float*)d_in[7];
  const float* Wdec = (const float*)d_in[8];
  const float* bdec = (const float*)d_in[9];
  float* out = (float*)d_out;

  const size_t seg = (size_t)NB * HH * MM * DD;
  unsigned short* Kf  = (unsigned short*)d_ws;
  unsigned short* Qf  = Kf + seg;
  unsigned short* Vt  = Qf + seg;
  unsigned short* DXp = Vt + seg;
  unsigned short* Wf  = DXp + seg;
  unsigned short* Wdf = Wf + 3 * 16384;

  prep_kernel<<<64, 256, 0, stream>>>(Wk, Wq, Wv, Wdec, Wf);
  proj_kernel<<<dim3(256, 12), 256, 0, stream>>>(x, Wf, bk, bq, bv, Kf, Qf, Vt);
  attn_kernel<<<dim3(8, HH, NB), 256, 0, stream>>>(Kf, Qf, Vt, x, DXp);
  dec_kernel<<<NB * MM / 64, 256, 0, stream>>>(DXp, Wdf, bdec, out);
}